// Round 3
// baseline (509.980 us; speedup 1.0000x reference)
//
#include <hip/hip_runtime.h>
#include <hip/hip_bf16.h>

#define HOPS 3
#define NA 50000
#define NP 100000
#define NIN 256
#define NHID 128
#define NOUT 64
#define CAP_A 64
#define CAP_P 40

typedef __attribute__((ext_vector_type(8))) short bf16x8;
typedef __attribute__((ext_vector_type(4))) float f32x4;
typedef unsigned short ushort_t;

__device__ inline short f2bf(float f) {
    __hip_bfloat16 h = __float2bfloat16(f);
    return *reinterpret_cast<short*>(&h);
}
__device__ inline float bf2f(unsigned short u) {
    unsigned v = ((unsigned)u) << 16;
    return __uint_as_float(v);
}

// ---------- W transpose+convert: Wt[n][k] = bf16(W[k][n]), W:[K][NHID] ----------
__global__ void wt_prep(const float* __restrict__ W, short* __restrict__ Wt, int K)
{
    int idx = blockIdx.x * 256 + threadIdx.x;
    if (idx >= NHID * K) return;
    int n = idx / K, k = idx - n * K;
    Wt[idx] = f2bf(W[(size_t)k * NHID + n]);
}

// ---------- f32 -> bf16 mirror ----------
__global__ void to_bf16(const float* __restrict__ in, ushort_t* __restrict__ out, int n8)
{
    int idx = blockIdx.x * 256 + threadIdx.x;
    if (idx >= n8) return;
    const float4* p = (const float4*)(in + (size_t)idx * 8);
    float4 v0 = p[0], v1 = p[1];
    union { ushort_t u[8]; int4 v; } pk;
    pk.u[0] = (ushort_t)f2bf(v0.x); pk.u[1] = (ushort_t)f2bf(v0.y);
    pk.u[2] = (ushort_t)f2bf(v0.z); pk.u[3] = (ushort_t)f2bf(v0.w);
    pk.u[4] = (ushort_t)f2bf(v1.x); pk.u[5] = (ushort_t)f2bf(v1.y);
    pk.u[6] = (ushort_t)f2bf(v1.z); pk.u[7] = (ushort_t)f2bf(v1.w);
    *(int4*)(out + (size_t)idx * 8) = pk.v;
}

// ---------- projection via MFMA, LDS-free: C[M,128] = relu(A[M,256] @ W + b) ----------
// Each wave owns 16 output rows. A-frag loaded directly from global (f32->bf16),
// B-frag directly from pre-transposed bf16 Wt [NHID][NIN]. No LDS, no barriers.
// mfma_f32_16x16x32_bf16: A row=l&15, k=(l>>4)*8+j ; B col=l&15 ; D col=l&15,row=(l>>4)*4+j
__global__ __launch_bounds__(256) void proj_mfma(const float* __restrict__ A,
                                                 const short* __restrict__ Wt,
                                                 const float* __restrict__ b,
                                                 float* __restrict__ C, int M)
{
    int tid = threadIdx.x;
    int wv = tid >> 6, l = tid & 63;
    int fl = l & 15, kg = l >> 4;
    int row0 = blockIdx.x * 64 + wv * 16;
    int arow = row0 + fl; if (arow >= M) arow = M - 1;
    const float* ap = A + (size_t)arow * NIN + kg * 8;
    const short* wp0 = Wt + (size_t)fl * NIN + kg * 8;

    f32x4 acc[8];
    #pragma unroll
    for (int c = 0; c < 8; ++c) acc[c] = (f32x4){0.f, 0.f, 0.f, 0.f};

    #pragma unroll 2
    for (int k0 = 0; k0 < NIN; k0 += 32) {
        float4 v0 = *(const float4*)(ap + k0);
        float4 v1 = *(const float4*)(ap + k0 + 4);
        union { short s[8]; bf16x8 v; } pk;
        pk.s[0] = f2bf(v0.x); pk.s[1] = f2bf(v0.y);
        pk.s[2] = f2bf(v0.z); pk.s[3] = f2bf(v0.w);
        pk.s[4] = f2bf(v1.x); pk.s[5] = f2bf(v1.y);
        pk.s[6] = f2bf(v1.z); pk.s[7] = f2bf(v1.w);
        #pragma unroll
        for (int c = 0; c < 8; ++c) {
            bf16x8 bfr = *(const bf16x8*)(wp0 + (size_t)c * 16 * NIN + k0);
            acc[c] = __builtin_amdgcn_mfma_f32_16x16x32_bf16(pk.v, bfr, acc[c], 0, 0, 0);
        }
    }

    #pragma unroll
    for (int c = 0; c < 8; ++c) {
        int col = c * 16 + fl;
        float bb = b[col];
        #pragma unroll
        for (int j = 0; j < 4; ++j) {
            int grow = row0 + kg * 4 + j;
            if (grow < M) {
                float v = acc[c][j] + bb;
                C[(size_t)grow * NHID + col] = fmaxf(v, 0.f);
            }
        }
    }
}

// ---------- output: C[M,64] = A[M,128] @ W[128,64] + b (f32 VALU) ----------
__global__ __launch_bounds__(256) void out_kernel(const float* __restrict__ A,
                                                  const float* __restrict__ W,
                                                  const float* __restrict__ b,
                                                  float* __restrict__ C, int M)
{
    __shared__ float As[32][68];
    __shared__ float Bs[32][68];
    int tid = threadIdx.x;
    int br = blockIdx.x * 64;
    int tx = tid & 15, ty = tid >> 4;
    int col = tx * 4, row0 = ty * 4;
    float acc[4][4] = {};
    for (int k0 = 0; k0 < NHID; k0 += 32) {
        #pragma unroll
        for (int i = 0; i < 2; ++i) {
            int f = tid + i * 256;
            int r = f >> 3;
            int k4 = (f & 7) * 4;
            int gr = br + r; if (gr >= M) gr = M - 1;
            const float4 v = *(const float4*)(A + (size_t)gr * NHID + k0 + k4);
            As[k4 + 0][r] = v.x; As[k4 + 1][r] = v.y;
            As[k4 + 2][r] = v.z; As[k4 + 3][r] = v.w;
        }
        #pragma unroll
        for (int i = 0; i < 2; ++i) {
            int f = tid + i * 256;
            int k = f >> 4;
            int n4 = (f & 15) * 4;
            const float4 v = *(const float4*)(W + (size_t)(k0 + k) * NOUT + n4);
            *(float4*)&Bs[k][n4] = v;
        }
        __syncthreads();
        #pragma unroll
        for (int kk = 0; kk < 32; ++kk) {
            float4 a = *(const float4*)&As[kk][row0];
            float4 bv = *(const float4*)&Bs[kk][col];
            float ar[4] = {a.x, a.y, a.z, a.w};
            float bc[4] = {bv.x, bv.y, bv.z, bv.w};
            #pragma unroll
            for (int r = 0; r < 4; ++r)
                #pragma unroll
                for (int c = 0; c < 4; ++c)
                    acc[r][c] += ar[r] * bc[c];
        }
        __syncthreads();
    }
    float4 bias = *(const float4*)(b + col);
    float bb[4] = {bias.x, bias.y, bias.z, bias.w};
    #pragma unroll
    for (int r = 0; r < 4; ++r) {
        int gr = br + row0 + r;
        if (gr < M) {
            float4 o = {acc[r][0] + bb[0], acc[r][1] + bb[1],
                        acc[r][2] + bb[2], acc[r][3] + bb[3]};
            *(float4*)(C + (size_t)gr * NOUT + col) = o;
        }
    }
}

// ---------- padded-CSR fill ----------
__global__ void fill_kernel(const int* __restrict__ s, const int* __restrict__ t,
                            int* __restrict__ cnt, int* __restrict__ slots,
                            int cap, int nE)
{
    int e = blockIdx.x * blockDim.x + threadIdx.x;
    if (e >= nE) return;
    int si = s[e];
    int c = atomicAdd(&cnt[si], 1);
    if (c < cap) slots[(size_t)si * cap + c] = t[e];
}

// ---------- one-time x-side scalars for ALL hops ----------
// x1[i] = x.attn1[i,e] ; w2[i] = exp(leaky(x.attn1[i,e] + x.attn2[i,e])) ; h1i = x.attn2[0,1-e]
__global__ void xdots_kernel(const float* __restrict__ x,
                             const float* __restrict__ attn1,
                             const float* __restrict__ attn2,
                             int etype,
                             float* __restrict__ x1, float* __restrict__ w2,
                             float* __restrict__ h1i, int N)
{
    int wid = (blockIdx.x * blockDim.x + threadIdx.x) >> 6;
    int lane = threadIdx.x & 63;
    if (wid >= N) return;
    float2 xv = *(const float2*)(x + (size_t)wid * NHID + lane * 2);
    float s[7];
    #pragma unroll
    for (int i = 0; i < 3; ++i) {
        float2 a1v = *(const float2*)(attn1 + (size_t)(i * 2 + etype) * NHID + lane * 2);
        float2 a2v = *(const float2*)(attn2 + (size_t)(i * 2 + etype) * NHID + lane * 2);
        s[i]     = xv.x * a1v.x + xv.y * a1v.y;
        s[3 + i] = xv.x * a2v.x + xv.y * a2v.y;
    }
    float2 a2o = *(const float2*)(attn2 + (size_t)(1 - etype) * NHID + lane * 2);
    s[6] = xv.x * a2o.x + xv.y * a2o.y;
    #pragma unroll
    for (int m = 32; m; m >>= 1)
        #pragma unroll
        for (int i = 0; i < 7; ++i) s[i] += __shfl_xor(s[i], m, 64);
    if (lane == 0) {
        #pragma unroll
        for (int i = 0; i < 3; ++i) {
            x1[(size_t)i * N + wid] = s[i];
            float v = s[i] + s[3 + i];
            v = v > 0.f ? v : 0.2f * v;
            w2[(size_t)i * N + wid] = __expf(v);
        }
        h1i[wid] = s[6];
    }
}

// ---------- aggregation: wave/node, 4 edge-groups x 16 feature-lanes, bf16 gather ----------
// Fused epilogue: elu, bf16 mirror write, optional f32 write, next-hop h1 dot.
__global__ void agg_kernel(const float* __restrict__ xself,
                           const ushort_t* __restrict__ hbf,
                           const float* __restrict__ x1, const float* __restrict__ w2s,
                           const float* __restrict__ h1,
                           const int* __restrict__ cnt, const int* __restrict__ slots,
                           const float* __restrict__ a2n,
                           float* __restrict__ houtf, ushort_t* __restrict__ houtb,
                           float* __restrict__ h1out,
                           int N, int cap, int writef)
{
    int wid = (blockIdx.x * blockDim.x + threadIdx.x) >> 6;
    int lane = threadIdx.x & 63;
    if (wid >= N) return;
    int g = lane >> 4, fl = lane & 15;
    int deg = cnt[wid];
    if (deg > cap) deg = cap;
    const int* sl = slots + (size_t)wid * cap;
    float x1v = x1[wid];
    float acc[8] = {};
    float div = 0.f;

    int e = g;
    int tnext = (e < deg) ? sl[e] : -1;
    while (tnext >= 0) {
        int t = tnext;
        e += 4;
        tnext = (e < deg) ? sl[e] : -1;    // prefetch next slot
        float sc = x1v + h1[t];
        sc = sc > 0.f ? sc : 0.2f * sc;
        float w = __expf(sc);
        div += w;
        union { int4 v; ushort_t u[8]; } hv;
        hv.v = *(const int4*)(hbf + (size_t)t * NHID + fl * 8);
        #pragma unroll
        for (int j = 0; j < 8; ++j) acc[j] += w * bf2f(hv.u[j]);
    }
    #pragma unroll
    for (int m = 16; m <= 32; m <<= 1) {
        #pragma unroll
        for (int j = 0; j < 8; ++j) acc[j] += __shfl_xor(acc[j], m, 64);
        div += __shfl_xor(div, m, 64);
    }
    if (g == 0) {
        float w2v = w2s[wid];
        const float4* xp = (const float4*)(xself + (size_t)wid * NHID + fl * 8);
        float4 x0 = xp[0], x1f = xp[1];
        float xs[8] = {x0.x, x0.y, x0.z, x0.w, x1f.x, x1f.y, x1f.z, x1f.w};
        #pragma unroll
        for (int j = 0; j < 8; ++j) acc[j] += w2v * xs[j];
        div += w2v;
        float inv = 1.f / div;
        float o[8];
        #pragma unroll
        for (int j = 0; j < 8; ++j) {
            float v = acc[j] * inv;
            o[j] = v > 0.f ? v : (__expf(v) - 1.f);
        }
        // next-hop h1 = o . a2n
        float s = 0.f;
        #pragma unroll
        for (int j = 0; j < 8; ++j) s += o[j] * a2n[fl * 8 + j];
        #pragma unroll
        for (int m = 1; m <= 8; m <<= 1) s += __shfl_xor(s, m, 64);
        if (fl == 0) h1out[wid] = s;
        // bf16 mirror
        union { ushort_t u[8]; int4 v; } pk;
        #pragma unroll
        for (int j = 0; j < 8; ++j) pk.u[j] = (ushort_t)f2bf(o[j]);
        *(int4*)(houtb + (size_t)wid * NHID + fl * 8) = pk.v;
        if (writef) {
            float4 s0 = {o[0], o[1], o[2], o[3]};
            float4 s1 = {o[4], o[5], o[6], o[7]};
            float4* op = (float4*)(houtf + (size_t)wid * NHID + fl * 8);
            op[0] = s0;
            op[1] = s1;
        }
    }
}

extern "C" void kernel_launch(void* const* d_in, const int* in_sizes, int n_in,
                              void* d_out, int out_size, void* d_ws, size_t ws_size,
                              hipStream_t stream)
{
    const float* x_A  = (const float*)d_in[0];
    const float* x_P  = (const float*)d_in[1];
    const int*   sAP  = (const int*)d_in[2];
    const int*   tAP  = (const int*)d_in[3];
    const int*   sPA  = (const int*)d_in[4];
    const int*   tPA  = (const int*)d_in[5];
    const float* W1_A = (const float*)d_in[6];
    const float* b1_A = (const float*)d_in[7];
    const float* W1_P = (const float*)d_in[8];
    const float* b1_P = (const float*)d_in[9];
    const float* attn1 = (const float*)d_in[10];
    const float* attn2 = (const float*)d_in[11];
    const float* W2   = (const float*)d_in[12];
    const float* b2   = (const float*)d_in[13];
    float* out = (float*)d_out;
    int nE = in_sizes[2];

    char* ws = (char*)d_ws;
    size_t off = 0;
    auto alloc = [&](size_t bytes) -> void* {
        void* p = ws + off;
        off += (bytes + 255) & ~(size_t)255;
        return p;
    };
    float* xA    = (float*)alloc((size_t)NA * NHID * 4);
    float* xP    = (float*)alloc((size_t)NP * NHID * 4);
    float* hAfin = (float*)alloc((size_t)NA * NHID * 4);
    ushort_t* xAbf  = (ushort_t*)alloc((size_t)NA * NHID * 2);
    ushort_t* xPbf  = (ushort_t*)alloc((size_t)NP * NHID * 2);
    ushort_t* hAbf0 = (ushort_t*)alloc((size_t)NA * NHID * 2);
    ushort_t* hAbf1 = (ushort_t*)alloc((size_t)NA * NHID * 2);
    ushort_t* hPbf  = (ushort_t*)alloc((size_t)NP * NHID * 2);
    float* x1A = (float*)alloc((size_t)3 * NA * 4);
    float* w2A = (float*)alloc((size_t)3 * NA * 4);
    float* x1P = (float*)alloc((size_t)3 * NP * 4);
    float* w2P = (float*)alloc((size_t)3 * NP * 4);
    float* h1Ai = (float*)alloc(NA * 4);
    float* h1A0 = (float*)alloc(NA * 4);
    float* h1A1 = (float*)alloc(NA * 4);
    float* h1Pi = (float*)alloc(NP * 4);
    float* h1Pb = (float*)alloc(NP * 4);
    int* cntA  = (int*)alloc(NA * 4);
    int* cntP  = (int*)alloc(NP * 4);
    int* slotsA = (int*)alloc((size_t)NA * CAP_A * 4);
    int* slotsP = (int*)alloc((size_t)NP * CAP_P * 4);
    short* WtA = (short*)alloc((size_t)NHID * NIN * 2);
    short* WtP = (short*)alloc((size_t)NHID * NIN * 2);

    // padded CSR (edge structure reused by all hops)
    hipMemsetAsync(cntA, 0, NA * 4, stream);
    hipMemsetAsync(cntP, 0, NP * 4, stream);
    fill_kernel<<<(nE + 255) / 256, 256, 0, stream>>>(sAP, tAP, cntA, slotsA, CAP_A, nE);
    fill_kernel<<<(nE + 255) / 256, 256, 0, stream>>>(sPA, tPA, cntP, slotsP, CAP_P, nE);

    // projections (bf16 MFMA, LDS-free)
    wt_prep<<<(NHID * NIN + 255) / 256, 256, 0, stream>>>(W1_A, WtA, NIN);
    wt_prep<<<(NHID * NIN + 255) / 256, 256, 0, stream>>>(W1_P, WtP, NIN);
    proj_mfma<<<(NA + 63) / 64, 256, 0, stream>>>(x_A, WtA, b1_A, xA, NA);
    proj_mfma<<<(NP + 63) / 64, 256, 0, stream>>>(x_P, WtP, b1_P, xP, NP);

    // bf16 mirrors of initial h
    to_bf16<<<((NA * NHID / 8) + 255) / 256, 256, 0, stream>>>(xA, xAbf, NA * NHID / 8);
    to_bf16<<<((NP * NHID / 8) + 255) / 256, 256, 0, stream>>>(xP, xPbf, NP * NHID / 8);

    // one-time x-side scalars for all hops
    xdots_kernel<<<(NA + 3) / 4, 256, 0, stream>>>(xA, attn1, attn2, 0, x1A, w2A, h1Ai, NA);
    xdots_kernel<<<(NP + 3) / 4, 256, 0, stream>>>(xP, attn1, attn2, 1, x1P, w2P, h1Pi, NP);

    const ushort_t* hAbf_cur = xAbf;
    const float*    h1A_cur  = h1Ai;
    const ushort_t* hPbf_cur = xPbf;
    const float*    h1P_cur  = h1Pi;
    ushort_t* hAbf_buf[2] = {hAbf0, hAbf1};
    float*    h1A_buf[2]  = {h1A0, h1A1};

    for (int i = 0; i < HOPS; ++i) {
        int last = (i == HOPS - 1);
        // a2 vectors for NEXT hop's h1 (dummy = base ptr on last hop)
        const float* a2nA = last ? attn2 : attn2 + (size_t)((i + 1) * 2 + 1) * NHID; // hA consumed by P-dir
        const float* a2nP = last ? attn2 : attn2 + (size_t)((i + 1) * 2 + 0) * NHID; // hP consumed by A-dir

        // A-direction: targets A, gathers from hP
        agg_kernel<<<(NA + 3) / 4, 256, 0, stream>>>(
            xA, hPbf_cur, x1A + (size_t)i * NA, w2A + (size_t)i * NA, h1P_cur,
            cntA, slotsA, a2nA, hAfin, hAbf_buf[i & 1], h1A_buf[i & 1],
            NA, CAP_A, last);
        if (!last) {
            // P-direction: targets P, gathers from (old) hA
            agg_kernel<<<(NP + 3) / 4, 256, 0, stream>>>(
                xP, hAbf_cur, x1P + (size_t)i * NP, w2P + (size_t)i * NP, h1A_cur,
                cntP, slotsP, a2nP, nullptr, hPbf, h1Pb,
                NP, CAP_P, 0);
            hAbf_cur = hAbf_buf[i & 1];
            h1A_cur  = h1A_buf[i & 1];
            hPbf_cur = hPbf;
            h1P_cur  = h1Pb;
        }
    }

    out_kernel<<<(NA + 63) / 64, 256, 0, stream>>>(hAfin, W2, b2, out, NA);
}

// Round 4
// 492.902 us; speedup vs baseline: 1.0346x; 1.0346x over previous
//
#include <hip/hip_runtime.h>
#include <hip/hip_bf16.h>

#define HOPS 3
#define NA 50000
#define NP 100000
#define NIN 256
#define NHID 128
#define NOUT 64
#define CAP_A 64
#define CAP_P 40

typedef __attribute__((ext_vector_type(8))) short bf16x8;
typedef __attribute__((ext_vector_type(4))) float f32x4;
typedef unsigned short ushort_t;

__device__ inline short f2bf(float f) {
    __hip_bfloat16 h = __float2bfloat16(f);
    return *reinterpret_cast<short*>(&h);
}
__device__ inline float bf2f(unsigned short u) {
    unsigned v = ((unsigned)u) << 16;
    return __uint_as_float(v);
}

// async global -> LDS, 16 bytes per lane (linear dest: base + lane*16)
__device__ inline void gload16(const void* g, void* l) {
    __builtin_amdgcn_global_load_lds(
        (const __attribute__((address_space(1))) unsigned int*)g,
        (__attribute__((address_space(3))) unsigned int*)l, 16, 0, 0);
}

// ---------- W transpose+convert: Wt[n][k] = bf16(W[k][n]), W:[K][N] ----------
__global__ void wt_prep(const float* __restrict__ W, short* __restrict__ Wt, int N, int K)
{
    int idx = blockIdx.x * 256 + threadIdx.x;
    if (idx >= N * K) return;
    int n = idx / K, k = idx - n * K;
    Wt[idx] = f2bf(W[(size_t)k * N + n]);
}

// ---------- projection: Cbf[M,128] = bf16(relu(A[M,256] @ W + b)) ----------
// 256 thr / 4 waves, tile 64 rows x 128 cols, BK=64, double-buffered LDS via
// global_load_lds, XOR-swizzled (chunk ^= row&7 on 16B units, both sides).
// mfma_f32_16x16x32_bf16: A row=l&15,k=(l>>4)*8+j ; B col=l&15 ; D col=l&15,row=(l>>4)*4+j
__global__ __launch_bounds__(256) void proj_mfma(const float* __restrict__ A,
        const short* __restrict__ Wt, const float* __restrict__ b,
        ushort_t* __restrict__ Cbf, int M)
{
    __shared__ float Abuf[2][64 * 64];      // 16KB x2
    const int tid = threadIdx.x;
    const int wv = tid >> 6, l = tid & 63;
    const int fl = l & 15, kg = l >> 4;
    const int br = blockIdx.x * 64;
    const int srow = l >> 4;                // 0..3 row within 1KB issue
    const int schk = l & 15;                // 16B chunk slot within row

    f32x4 acc[8];
    #pragma unroll
    for (int c = 0; c < 8; ++c) acc[c] = (f32x4){0.f, 0.f, 0.f, 0.f};

    auto stage = [&](int buf, int k0) {
        #pragma unroll
        for (int i = 0; i < 4; ++i) {
            int r = (wv * 4 + i) * 4 + srow;
            int gr = br + r; if (gr >= M) gr = M - 1;
            int ck = (schk ^ (r & 7)) * 4;   // inverse-swizzled source (f32 idx)
            gload16(A + (size_t)gr * NIN + k0 + ck, &Abuf[buf][(wv * 4 + i) * 256]);
        }
    };

    stage(0, 0);
    __syncthreads();                          // drain buf0

    const int R = wv * 16 + fl;               // this lane's A-frag row
    const int rx = R & 7;

    for (int t = 0; t < 4; ++t) {
        const int k0 = t * 64;
        if (t < 3) stage((t + 1) & 1, k0 + 64);   // async prefetch next chunk

        bf16x8 Bf[16];
        #pragma unroll
        for (int ks = 0; ks < 2; ++ks)
            #pragma unroll
            for (int c = 0; c < 8; ++c)
                Bf[ks * 8 + c] = *(const bf16x8*)(Wt + (size_t)(c * 16 + fl) * NIN
                                                  + k0 + ks * 32 + kg * 8);
        const float* buf = &Abuf[t & 1][0];
        #pragma unroll
        for (int ks = 0; ks < 2; ++ks) {
            int c0 = (ks * 8 + kg * 2) ^ rx;
            int c1 = (ks * 8 + kg * 2 + 1) ^ rx;
            float4 q0 = *(const float4*)(buf + R * 64 + c0 * 4);
            float4 q1 = *(const float4*)(buf + R * 64 + c1 * 4);
            union { short s[8]; bf16x8 v; } pk;
            pk.s[0] = f2bf(q0.x); pk.s[1] = f2bf(q0.y);
            pk.s[2] = f2bf(q0.z); pk.s[3] = f2bf(q0.w);
            pk.s[4] = f2bf(q1.x); pk.s[5] = f2bf(q1.y);
            pk.s[6] = f2bf(q1.z); pk.s[7] = f2bf(q1.w);
            #pragma unroll
            for (int c = 0; c < 8; ++c)
                acc[c] = __builtin_amdgcn_mfma_f32_16x16x32_bf16(pk.v, Bf[ks * 8 + c],
                                                                 acc[c], 0, 0, 0);
        }
        __syncthreads();   // drains prefetch; protects buffer reuse
    }

    #pragma unroll
    for (int c = 0; c < 8; ++c) {
        int col = c * 16 + fl;
        float bb = b[col];
        #pragma unroll
        for (int j = 0; j < 4; ++j) {
            int grow = br + wv * 16 + kg * 4 + j;
            if (grow < M) {
                float v = fmaxf(acc[c][j] + bb, 0.f);
                Cbf[(size_t)grow * NHID + col] = (ushort_t)f2bf(v);
            }
        }
    }
}

// ---------- output: C[M,64] = Abf[M,128] @ W2 + b2, single-stage MFMA ----------
__global__ __launch_bounds__(256) void out_mfma(const ushort_t* __restrict__ Abf,
        const short* __restrict__ Wt, const float* __restrict__ b,
        float* __restrict__ C, int M)
{
    __shared__ ushort_t Sb[64 * 128];   // 16KB, rows of 128 bf16 (16 x 16B chunks)
    const int tid = threadIdx.x;
    const int wv = tid >> 6, l = tid & 63;
    const int fl = l & 15, kg = l >> 4;
    const int br = blockIdx.x * 64;
    const int srow = l >> 4, schk = l & 15;

    #pragma unroll
    for (int i = 0; i < 4; ++i) {
        int r = (wv * 4 + i) * 4 + srow;
        int gr = br + r; if (gr >= M) gr = M - 1;
        int ck = (schk ^ (r & 7)) * 8;   // bf16 idx of inverse-swizzled 16B chunk
        gload16(Abf + (size_t)gr * NHID + ck, &Sb[(wv * 4 + i) * 512]);
    }

    f32x4 acc[4];
    #pragma unroll
    for (int c = 0; c < 4; ++c) acc[c] = (f32x4){0.f, 0.f, 0.f, 0.f};

    bf16x8 Bf[16];
    #pragma unroll
    for (int ks = 0; ks < 4; ++ks)
        #pragma unroll
        for (int cc = 0; cc < 4; ++cc)
            Bf[ks * 4 + cc] = *(const bf16x8*)(Wt + (size_t)(cc * 16 + fl) * NHID
                                               + ks * 32 + kg * 8);
    __syncthreads();

    const int R = wv * 16 + fl;
    const int rx = R & 7;
    #pragma unroll
    for (int ks = 0; ks < 4; ++ks) {
        int chunk = (ks * 4 + kg) ^ rx;
        bf16x8 af = *(const bf16x8*)&Sb[R * 128 + chunk * 8];
        #pragma unroll
        for (int cc = 0; cc < 4; ++cc)
            acc[cc] = __builtin_amdgcn_mfma_f32_16x16x32_bf16(af, Bf[ks * 4 + cc],
                                                              acc[cc], 0, 0, 0);
    }

    #pragma unroll
    for (int cc = 0; cc < 4; ++cc) {
        int col = cc * 16 + fl;
        float bb = b[col];
        #pragma unroll
        for (int j = 0; j < 4; ++j) {
            int grow = br + wv * 16 + kg * 4 + j;
            if (grow < M) C[(size_t)grow * NOUT + col] = acc[cc][j] + bb;
        }
    }
}

// ---------- padded-CSR fill: slots[.x]=t, pos[e] = slot index ----------
__global__ void fill_kernel(const int* __restrict__ s, const int* __restrict__ t,
                            int* __restrict__ cnt, int2* __restrict__ slots,
                            int* __restrict__ pos, int cap, int nE)
{
    int e = blockIdx.x * blockDim.x + threadIdx.x;
    if (e >= nE) return;
    int si = s[e];
    int c = atomicAdd(&cnt[si], 1);
    if (c < cap) { slots[(size_t)si * cap + c].x = t[e]; pos[e] = si * cap + c; }
    else pos[e] = -1;
}

// ---------- one-time x-side scalars for ALL hops (bf16 x) ----------
__global__ void xdots_kernel(const ushort_t* __restrict__ x,
                             const float* __restrict__ attn1,
                             const float* __restrict__ attn2,
                             int etype,
                             float* __restrict__ x1, float* __restrict__ w2,
                             float* __restrict__ h1i, int N)
{
    int wid = (blockIdx.x * blockDim.x + threadIdx.x) >> 6;
    int lane = threadIdx.x & 63;
    if (wid >= N) return;
    ushort2 xv = *(const ushort2*)(x + (size_t)wid * NHID + lane * 2);
    float xa = bf2f(xv.x), xb = bf2f(xv.y);
    float s[7];
    #pragma unroll
    for (int i = 0; i < 3; ++i) {
        float2 a1v = *(const float2*)(attn1 + (size_t)(i * 2 + etype) * NHID + lane * 2);
        float2 a2v = *(const float2*)(attn2 + (size_t)(i * 2 + etype) * NHID + lane * 2);
        s[i]     = xa * a1v.x + xb * a1v.y;
        s[3 + i] = xa * a2v.x + xb * a2v.y;
    }
    float2 a2o = *(const float2*)(attn2 + (size_t)(1 - etype) * NHID + lane * 2);
    s[6] = xa * a2o.x + xb * a2o.y;
    #pragma unroll
    for (int m = 32; m; m >>= 1)
        #pragma unroll
        for (int i = 0; i < 7; ++i) s[i] += __shfl_xor(s[i], m, 64);
    if (lane == 0) {
        #pragma unroll
        for (int i = 0; i < 3; ++i) {
            x1[(size_t)i * N + wid] = s[i];
            float v = s[i] + s[3 + i];
            v = v > 0.f ? v : 0.2f * v;
            w2[(size_t)i * N + wid] = __expf(v);
        }
        h1i[wid] = s[6];
    }
}

// ---------- edge-parallel scores: slots[pos].y = exp(leaky(x1[s]+h1[t])) ----------
__global__ void score_kernel(const int* __restrict__ sA, const int* __restrict__ tA,
        const int* __restrict__ posA, const float* __restrict__ x1A, const float* __restrict__ h1P,
        const int* __restrict__ sP, const int* __restrict__ tP,
        const int* __restrict__ posP, const float* __restrict__ x1P, const float* __restrict__ h1A,
        int2* __restrict__ slotsA, int2* __restrict__ slotsP, int nEA, int nEP)
{
    int e = blockIdx.x * 256 + threadIdx.x;
    if (e < nEA) {
        int p = posA[e];
        if (p >= 0) {
            float v = x1A[sA[e]] + h1P[tA[e]];
            v = v > 0.f ? v : 0.2f * v;
            slotsA[p].y = __float_as_int(__expf(v));
        }
    } else if (e < nEA + nEP) {
        int e2 = e - nEA;
        int p = posP[e2];
        if (p >= 0) {
            float v = x1P[sP[e2]] + h1A[tP[e2]];
            v = v > 0.f ? v : 0.2f * v;
            slotsP[p].y = __float_as_int(__expf(v));
        }
    }
}

// ---------- fused A+P aggregation: wave/node, 4 edge-groups x 16 lanes, unroll 2 ----------
__global__ __launch_bounds__(256) void agg_fused(
    const ushort_t* __restrict__ xAbf, const ushort_t* __restrict__ xPbf,
    const ushort_t* __restrict__ hAg, const ushort_t* __restrict__ hPg,
    const float* __restrict__ w2A, const float* __restrict__ w2P,
    const int* __restrict__ cntA, const int2* __restrict__ slotsA,
    const int* __restrict__ cntP, const int2* __restrict__ slotsP,
    const float* __restrict__ a2nA, const float* __restrict__ a2nP,
    ushort_t* __restrict__ hAout, ushort_t* __restrict__ hPout,
    float* __restrict__ h1Aout, float* __restrict__ h1Pout,
    int nodes)
{
    int wid = (blockIdx.x * blockDim.x + threadIdx.x) >> 6;
    int lane = threadIdx.x & 63;
    if (wid >= nodes) return;
    int g = lane >> 4, fl = lane & 15;
    bool isA = wid < NA;
    int n = isA ? wid : wid - NA;
    int deg; const int2* sl; const ushort_t* hbf;
    if (isA) { deg = cntA[n]; if (deg > CAP_A) deg = CAP_A; sl = slotsA + (size_t)n * CAP_A; hbf = hPg; }
    else     { deg = cntP[n]; if (deg > CAP_P) deg = CAP_P; sl = slotsP + (size_t)n * CAP_P; hbf = hAg; }

    float acc[8] = {};
    float div = 0.f;
    for (int e = g; e < deg; e += 8) {
        int2 q0 = sl[e];
        int e1 = e + 4;
        int2 q1 = (e1 < deg) ? sl[e1] : make_int2(q0.x, 0);
        union { int4 v; ushort_t u[8]; } h0, h1v;
        h0.v  = *(const int4*)(hbf + (size_t)q0.x * NHID + fl * 8);
        h1v.v = *(const int4*)(hbf + (size_t)q1.x * NHID + fl * 8);
        float w0 = __int_as_float(q0.y);
        float w1 = __int_as_float(q1.y);
        div += w0 + w1;
        #pragma unroll
        for (int j = 0; j < 8; ++j)
            acc[j] += w0 * bf2f(h0.u[j]) + w1 * bf2f(h1v.u[j]);
    }
    #pragma unroll
    for (int m = 16; m <= 32; m <<= 1) {
        #pragma unroll
        for (int j = 0; j < 8; ++j) acc[j] += __shfl_xor(acc[j], m, 64);
        div += __shfl_xor(div, m, 64);
    }
    if (g == 0) {
        float w2v = isA ? w2A[n] : w2P[n];
        union { int4 v; ushort_t u[8]; } xv;
        xv.v = *(const int4*)((isA ? xAbf : xPbf) + (size_t)n * NHID + fl * 8);
        #pragma unroll
        for (int j = 0; j < 8; ++j) acc[j] += w2v * bf2f(xv.u[j]);
        div += w2v;
        float inv = 1.f / div;
        const float* a2 = isA ? a2nA : a2nP;
        float o[8], s = 0.f;
        #pragma unroll
        for (int j = 0; j < 8; ++j) {
            float v = acc[j] * inv;
            o[j] = v > 0.f ? v : (__expf(v) - 1.f);
            s += o[j] * a2[fl * 8 + j];
        }
        #pragma unroll
        for (int m = 1; m <= 8; m <<= 1) s += __shfl_xor(s, m, 64);
        union { ushort_t u[8]; int4 v; } pk;
        #pragma unroll
        for (int j = 0; j < 8; ++j) pk.u[j] = (ushort_t)f2bf(o[j]);
        *(int4*)((isA ? hAout : hPout) + (size_t)n * NHID + fl * 8) = pk.v;
        if (fl == 0) (isA ? h1Aout : h1Pout)[n] = s;
    }
}

extern "C" void kernel_launch(void* const* d_in, const int* in_sizes, int n_in,
                              void* d_out, int out_size, void* d_ws, size_t ws_size,
                              hipStream_t stream)
{
    const float* x_A  = (const float*)d_in[0];
    const float* x_P  = (const float*)d_in[1];
    const int*   sAP  = (const int*)d_in[2];
    const int*   tAP  = (const int*)d_in[3];
    const int*   sPA  = (const int*)d_in[4];
    const int*   tPA  = (const int*)d_in[5];
    const float* W1_A = (const float*)d_in[6];
    const float* b1_A = (const float*)d_in[7];
    const float* W1_P = (const float*)d_in[8];
    const float* b1_P = (const float*)d_in[9];
    const float* attn1 = (const float*)d_in[10];
    const float* attn2 = (const float*)d_in[11];
    const float* W2   = (const float*)d_in[12];
    const float* b2   = (const float*)d_in[13];
    float* out = (float*)d_out;
    int nE = in_sizes[2];

    char* ws = (char*)d_ws;
    size_t off = 0;
    auto alloc = [&](size_t bytes) -> void* {
        void* p = ws + off;
        off += (bytes + 255) & ~(size_t)255;
        return p;
    };
    ushort_t* xAbf  = (ushort_t*)alloc((size_t)NA * NHID * 2);
    ushort_t* xPbf  = (ushort_t*)alloc((size_t)NP * NHID * 2);
    ushort_t* hAbf[2] = {(ushort_t*)alloc((size_t)NA * NHID * 2),
                         (ushort_t*)alloc((size_t)NA * NHID * 2)};
    ushort_t* hPbf[2] = {(ushort_t*)alloc((size_t)NP * NHID * 2),
                         (ushort_t*)alloc((size_t)NP * NHID * 2)};
    float* x1A = (float*)alloc((size_t)3 * NA * 4);
    float* w2A = (float*)alloc((size_t)3 * NA * 4);
    float* x1P = (float*)alloc((size_t)3 * NP * 4);
    float* w2P = (float*)alloc((size_t)3 * NP * 4);
    float* h1Ai = (float*)alloc(NA * 4);
    float* h1Pi = (float*)alloc(NP * 4);
    float* h1Ab[2] = {(float*)alloc(NA * 4), (float*)alloc(NA * 4)};
    float* h1Pb[2] = {(float*)alloc(NP * 4), (float*)alloc(NP * 4)};
    int* cntA  = (int*)alloc(NA * 4);
    int* cntP  = (int*)alloc(NP * 4);
    int2* slotsA = (int2*)alloc((size_t)NA * CAP_A * 8);
    int2* slotsP = (int2*)alloc((size_t)NP * CAP_P * 8);
    int* posA = (int*)alloc((size_t)nE * 4);
    int* posP = (int*)alloc((size_t)nE * 4);
    short* WtA = (short*)alloc((size_t)NHID * NIN * 2);
    short* WtP = (short*)alloc((size_t)NHID * NIN * 2);
    short* Wt2 = (short*)alloc((size_t)NOUT * NHID * 2);

    // padded CSR
    hipMemsetAsync(cntA, 0, NA * 4, stream);
    hipMemsetAsync(cntP, 0, NP * 4, stream);
    fill_kernel<<<(nE + 255) / 256, 256, 0, stream>>>(sAP, tAP, cntA, slotsA, posA, CAP_A, nE);
    fill_kernel<<<(nE + 255) / 256, 256, 0, stream>>>(sPA, tPA, cntP, slotsP, posP, CAP_P, nE);

    // weights -> bf16 transposed
    wt_prep<<<(NHID * NIN + 255) / 256, 256, 0, stream>>>(W1_A, WtA, NHID, NIN);
    wt_prep<<<(NHID * NIN + 255) / 256, 256, 0, stream>>>(W1_P, WtP, NHID, NIN);
    wt_prep<<<(NOUT * NHID + 255) / 256, 256, 0, stream>>>(W2, Wt2, NOUT, NHID);

    // projections -> bf16 h0
    proj_mfma<<<(NA + 63) / 64, 256, 0, stream>>>(x_A, WtA, b1_A, xAbf, NA);
    proj_mfma<<<(NP + 63) / 64, 256, 0, stream>>>(x_P, WtP, b1_P, xPbf, NP);

    // x-side scalars for all hops
    xdots_kernel<<<(NA + 3) / 4, 256, 0, stream>>>(xAbf, attn1, attn2, 0, x1A, w2A, h1Ai, NA);
    xdots_kernel<<<(NP + 3) / 4, 256, 0, stream>>>(xPbf, attn1, attn2, 1, x1P, w2P, h1Pi, NP);

    const ushort_t* hAg = xAbf;
    const ushort_t* hPg = xPbf;
    const float* h1Ac = h1Ai;
    const float* h1Pc = h1Pi;

    for (int i = 0; i < HOPS; ++i) {
        int last = (i == HOPS - 1);
        int nEP_eff = last ? 0 : nE;
        score_kernel<<<(nE + nEP_eff + 255) / 256, 256, 0, stream>>>(
            sAP, tAP, posA, x1A + (size_t)i * NA, h1Pc,
            sPA, tPA, posP, x1P + (size_t)i * NP, h1Ac,
            slotsA, slotsP, nE, nEP_eff);

        int nodes = last ? NA : (NA + NP);
        const float* a2nA_ = last ? attn2 : attn2 + (size_t)((i + 1) * 2 + 1) * NHID;
        const float* a2nP_ = last ? attn2 : attn2 + (size_t)((i + 1) * 2 + 0) * NHID;
        agg_fused<<<(nodes + 3) / 4, 256, 0, stream>>>(
            xAbf, xPbf, hAg, hPg,
            w2A + (size_t)i * NA, w2P + (size_t)i * NP,
            cntA, slotsA, cntP, slotsP,
            a2nA_, a2nP_,
            hAbf[i & 1], hPbf[i & 1], h1Ab[i & 1], h1Pb[i & 1],
            nodes);
        hAg = hAbf[i & 1]; hPg = hPbf[i & 1];
        h1Ac = h1Ab[i & 1]; h1Pc = h1Pb[i & 1];
    }

    out_mfma<<<(NA + 63) / 64, 256, 0, stream>>>(hAg, Wt2, b2, out, NA);
}

// Round 5
// 478.773 us; speedup vs baseline: 1.0652x; 1.0295x over previous
//
#include <hip/hip_runtime.h>
#include <hip/hip_bf16.h>

#define HOPS 3
#define NA 50000
#define NP 100000
#define NIN 256
#define NHID 128
#define NOUT 64
#define CAP_A 64
#define CAP_P 40

typedef __attribute__((ext_vector_type(8))) short bf16x8;
typedef __attribute__((ext_vector_type(4))) float f32x4;
typedef unsigned short ushort_t;

__device__ inline short f2bf(float f) {
    __hip_bfloat16 h = __float2bfloat16(f);
    return *reinterpret_cast<short*>(&h);
}
__device__ inline float bf2f(unsigned short u) {
    unsigned v = ((unsigned)u) << 16;
    return __uint_as_float(v);
}

// async global -> LDS, 16 bytes per lane (linear dest: base + lane*16)
__device__ inline void gload16(const void* g, void* l) {
    __builtin_amdgcn_global_load_lds(
        (const __attribute__((address_space(1))) unsigned int*)g,
        (__attribute__((address_space(3))) unsigned int*)l, 16, 0, 0);
}

// ---------- all weight transposes+converts in one launch ----------
__global__ void prep_all(const float* __restrict__ W1_A, const float* __restrict__ W1_P,
                         const float* __restrict__ W2,
                         short* __restrict__ WtA, short* __restrict__ WtP,
                         short* __restrict__ Wt2)
{
    int idx = blockIdx.x * 256 + threadIdx.x;
    const int S1 = NHID * NIN;
    if (idx < S1) {
        int n = idx / NIN, k = idx - n * NIN;
        WtA[idx] = f2bf(W1_A[(size_t)k * NHID + n]);
    } else if (idx < 2 * S1) {
        int j = idx - S1;
        int n = j / NIN, k = j - n * NIN;
        WtP[j] = f2bf(W1_P[(size_t)k * NHID + n]);
    } else if (idx < 2 * S1 + NOUT * NHID) {
        int j = idx - 2 * S1;
        int n = j / NHID, k = j - n * NHID;
        Wt2[j] = f2bf(W2[(size_t)k * NOUT + n]);
    }
}

// ---------- merged projection: Cbf = bf16(relu(X @ W1 + b1)) for A and P ----------
// 256 thr / 4 waves; each wave owns 16 rows and its OWN LDS region -> no
// __syncthreads in the K-loop. Reg-staged depth-2 pipeline: global->reg
// (exact compiler vmcnt) -> ds_write -> ds_read fragments. LDS rows padded
// to 68 floats for uniform bank spread.
__global__ __launch_bounds__(256) void proj_mfma(
        const float* __restrict__ xA, const float* __restrict__ xP,
        const short* __restrict__ WtA_, const short* __restrict__ WtP_,
        const float* __restrict__ bA, const float* __restrict__ bP,
        ushort_t* __restrict__ CA, ushort_t* __restrict__ CP, int gA)
{
    __shared__ float Abuf[4][2][16][68];   // 34 KB
    const int tid = threadIdx.x;
    const int wv = tid >> 6, l = tid & 63;
    const int fl = l & 15, kg = l >> 4;     // MFMA fragment roles
    const int lr = l >> 2, cq = l & 3;      // staging roles (row, 16B slot)

    const int bid = blockIdx.x;
    const bool isA = bid < gA;
    const float* A = isA ? xA : xP;
    const short* Wt = isA ? WtA_ : WtP_;
    const float* bias = isA ? bA : bP;
    ushort_t* C = isA ? CA : CP;
    const int M = isA ? NA : NP;
    const int Rbase = (isA ? bid : bid - gA) * 64;

    int gr = Rbase + wv * 16 + lr; if (gr >= M) gr = M - 1;
    const float* srcrow = A + (size_t)gr * NIN;

    f32x4 acc[8];
    #pragma unroll
    for (int c = 0; c < 8; ++c) acc[c] = (f32x4){0.f, 0.f, 0.f, 0.f};

    auto LOADR = [&](float4* pre, int k0) {
        #pragma unroll
        for (int i = 0; i < 4; ++i)
            pre[i] = *(const float4*)(srcrow + k0 + cq * 4 + i * 16);
    };
    auto WRITE = [&](int b, const float4* pre) {
        #pragma unroll
        for (int i = 0; i < 4; ++i)
            *(float4*)(&Abuf[wv][b][lr][cq * 4 + i * 16]) = pre[i];
    };
    auto COMPUTE = [&](int b, int k0) {
        bf16x8 Bf[16];
        #pragma unroll
        for (int ks = 0; ks < 2; ++ks)
            #pragma unroll
            for (int c = 0; c < 8; ++c)
                Bf[ks * 8 + c] = *(const bf16x8*)(Wt + (size_t)(c * 16 + fl) * NIN
                                                  + k0 + ks * 32 + kg * 8);
        const float* B0 = &Abuf[wv][b][0][0];
        #pragma unroll
        for (int ks = 0; ks < 2; ++ks) {
            float4 q0 = *(const float4*)(B0 + fl * 68 + (ks * 8 + kg * 2) * 4);
            float4 q1 = *(const float4*)(B0 + fl * 68 + (ks * 8 + kg * 2) * 4 + 4);
            union { short s[8]; bf16x8 v; } pk;
            pk.s[0] = f2bf(q0.x); pk.s[1] = f2bf(q0.y);
            pk.s[2] = f2bf(q0.z); pk.s[3] = f2bf(q0.w);
            pk.s[4] = f2bf(q1.x); pk.s[5] = f2bf(q1.y);
            pk.s[6] = f2bf(q1.z); pk.s[7] = f2bf(q1.w);
            #pragma unroll
            for (int c = 0; c < 8; ++c)
                acc[c] = __builtin_amdgcn_mfma_f32_16x16x32_bf16(pk.v, Bf[ks * 8 + c],
                                                                 acc[c], 0, 0, 0);
        }
    };

    float4 pa[4], pb[4];
    LOADR(pa, 0);
    LOADR(pb, 64);
    WRITE(0, pa);
    LOADR(pa, 128);
    COMPUTE(0, 0);
    WRITE(1, pb);
    LOADR(pb, 192);
    COMPUTE(1, 64);
    WRITE(0, pa);
    COMPUTE(0, 128);
    WRITE(1, pb);
    COMPUTE(1, 192);

    #pragma unroll
    for (int c = 0; c < 8; ++c) {
        int col = c * 16 + fl;
        float bb = bias[col];
        #pragma unroll
        for (int j = 0; j < 4; ++j) {
            int grow = Rbase + wv * 16 + kg * 4 + j;
            if (grow < M) {
                float v = fmaxf(acc[c][j] + bb, 0.f);
                C[(size_t)grow * NHID + col] = (ushort_t)f2bf(v);
            }
        }
    }
}

// ---------- output: C[M,64] = Abf[M,128] @ W2 + b2, single-stage MFMA ----------
__global__ __launch_bounds__(256) void out_mfma(const ushort_t* __restrict__ Abf,
        const short* __restrict__ Wt, const float* __restrict__ b,
        float* __restrict__ C, int M)
{
    __shared__ ushort_t Sb[64 * 128];   // 16KB
    const int tid = threadIdx.x;
    const int wv = tid >> 6, l = tid & 63;
    const int fl = l & 15, kg = l >> 4;
    const int br = blockIdx.x * 64;
    const int srow = l >> 4, schk = l & 15;

    #pragma unroll
    for (int i = 0; i < 4; ++i) {
        int r = (wv * 4 + i) * 4 + srow;
        int gr = br + r; if (gr >= M) gr = M - 1;
        int ck = (schk ^ (r & 7)) * 8;
        gload16(Abf + (size_t)gr * NHID + ck, &Sb[(wv * 4 + i) * 512]);
    }

    f32x4 acc[4];
    #pragma unroll
    for (int c = 0; c < 4; ++c) acc[c] = (f32x4){0.f, 0.f, 0.f, 0.f};

    bf16x8 Bf[16];
    #pragma unroll
    for (int ks = 0; ks < 4; ++ks)
        #pragma unroll
        for (int cc = 0; cc < 4; ++cc)
            Bf[ks * 4 + cc] = *(const bf16x8*)(Wt + (size_t)(cc * 16 + fl) * NHID
                                               + ks * 32 + kg * 8);
    __syncthreads();

    const int R = wv * 16 + fl;
    const int rx = R & 7;
    #pragma unroll
    for (int ks = 0; ks < 4; ++ks) {
        int chunk = (ks * 4 + kg) ^ rx;
        bf16x8 af = *(const bf16x8*)&Sb[R * 128 + chunk * 8];
        #pragma unroll
        for (int cc = 0; cc < 4; ++cc)
            acc[cc] = __builtin_amdgcn_mfma_f32_16x16x32_bf16(af, Bf[ks * 4 + cc],
                                                              acc[cc], 0, 0, 0);
    }

    #pragma unroll
    for (int cc = 0; cc < 4; ++cc) {
        int col = cc * 16 + fl;
        float bb = b[col];
        #pragma unroll
        for (int j = 0; j < 4; ++j) {
            int grow = br + wv * 16 + kg * 4 + j;
            if (grow < M) C[(size_t)grow * NOUT + col] = acc[cc][j] + bb;
        }
    }
}

// ---------- merged padded-CSR fill ----------
__global__ void fill_kernel(const int* __restrict__ sA, const int* __restrict__ tA,
                            const int* __restrict__ sP, const int* __restrict__ tP,
                            int* __restrict__ cntA, int* __restrict__ slotsA,
                            int* __restrict__ cntP, int* __restrict__ slotsP, int nE)
{
    int e = blockIdx.x * 256 + threadIdx.x;
    if (e < nE) {
        int si = sA[e];
        int c = atomicAdd(&cntA[si], 1);
        if (c < CAP_A) slotsA[(size_t)si * CAP_A + c] = tA[e];
    } else if (e < 2 * nE) {
        int k = e - nE;
        int si = sP[k];
        int c = atomicAdd(&cntP[si], 1);
        if (c < CAP_P) slotsP[(size_t)si * CAP_P + c] = tP[k];
    }
}

// ---------- merged x-side scalars for ALL hops ----------
__global__ void xdots_kernel(const ushort_t* __restrict__ xAbf, const ushort_t* __restrict__ xPbf,
                             const float* __restrict__ attn1, const float* __restrict__ attn2,
                             float* __restrict__ x1A, float* __restrict__ w2A, float* __restrict__ h1Ai,
                             float* __restrict__ x1P, float* __restrict__ w2P, float* __restrict__ h1Pi)
{
    int wid = (blockIdx.x * blockDim.x + threadIdx.x) >> 6;
    int lane = threadIdx.x & 63;
    if (wid >= NA + NP) return;
    bool isA = wid < NA;
    int n = isA ? wid : wid - NA;
    int etype = isA ? 0 : 1;
    const ushort_t* x = (isA ? xAbf : xPbf) + (size_t)n * NHID;
    ushort2 xv = *(const ushort2*)(x + lane * 2);
    float xa = bf2f(xv.x), xb = bf2f(xv.y);
    float s[7];
    #pragma unroll
    for (int i = 0; i < 3; ++i) {
        float2 a1v = *(const float2*)(attn1 + (size_t)(i * 2 + etype) * NHID + lane * 2);
        float2 a2v = *(const float2*)(attn2 + (size_t)(i * 2 + etype) * NHID + lane * 2);
        s[i]     = xa * a1v.x + xb * a1v.y;
        s[3 + i] = xa * a2v.x + xb * a2v.y;
    }
    float2 a2o = *(const float2*)(attn2 + (size_t)(1 - etype) * NHID + lane * 2);
    s[6] = xa * a2o.x + xb * a2o.y;
    #pragma unroll
    for (int m = 32; m; m >>= 1)
        #pragma unroll
        for (int i = 0; i < 7; ++i) s[i] += __shfl_xor(s[i], m, 64);
    if (lane == 0) {
        int N = isA ? NA : NP;
        float* x1 = isA ? x1A : x1P;
        float* w2 = isA ? w2A : w2P;
        #pragma unroll
        for (int i = 0; i < 3; ++i) {
            x1[(size_t)i * N + n] = s[i];
            float v = s[i] + s[3 + i];
            v = v > 0.f ? v : 0.2f * v;
            w2[(size_t)i * N + n] = __expf(v);
        }
        (isA ? h1Ai : h1Pi)[n] = s[6];
    }
}

// ---------- fused A+P aggregation, scores computed in-kernel ----------
// wave/node, 8 edge-groups x 8 feature-lanes (16 floats each), unroll 2
__global__ __launch_bounds__(256) void agg_fused(
    const ushort_t* __restrict__ xAbf, const ushort_t* __restrict__ xPbf,
    const ushort_t* __restrict__ hAg, const ushort_t* __restrict__ hPg,
    const float* __restrict__ x1Ah, const float* __restrict__ x1Ph,
    const float* __restrict__ w2Ah, const float* __restrict__ w2Ph,
    const float* __restrict__ h1Agc, const float* __restrict__ h1Pgc,
    const int* __restrict__ cntA, const int* __restrict__ slotsA,
    const int* __restrict__ cntP, const int* __restrict__ slotsP,
    const float* __restrict__ a2nA, const float* __restrict__ a2nP,
    ushort_t* __restrict__ hAout, ushort_t* __restrict__ hPout,
    float* __restrict__ h1Aout, float* __restrict__ h1Pout,
    int nodes)
{
    int wid = (blockIdx.x * blockDim.x + threadIdx.x) >> 6;
    int lane = threadIdx.x & 63;
    if (wid >= nodes) return;
    int g = lane >> 3, fl = lane & 7;
    bool isA = wid < NA;
    int n = isA ? wid : wid - NA;
    int deg; const int* sl; const ushort_t* hbf; const float* h1g; float x1v;
    if (isA) {
        deg = cntA[n]; if (deg > CAP_A) deg = CAP_A;
        sl = slotsA + (size_t)n * CAP_A; hbf = hPg; h1g = h1Pgc; x1v = x1Ah[n];
    } else {
        deg = cntP[n]; if (deg > CAP_P) deg = CAP_P;
        sl = slotsP + (size_t)n * CAP_P; hbf = hAg; h1g = h1Agc; x1v = x1Ph[n];
    }

    float acc[16] = {};
    float div = 0.f;
    for (int e = g; e < deg; e += 16) {
        int e1 = e + 8;
        int t0 = sl[e];
        bool has1 = (e1 < deg);
        int t1 = has1 ? sl[e1] : t0;
        float h10 = h1g[t0], h11 = h1g[t1];
        const int4* p0 = (const int4*)(hbf + (size_t)t0 * NHID + fl * 16);
        const int4* p1 = (const int4*)(hbf + (size_t)t1 * NHID + fl * 16);
        int4 r00 = p0[0], r01 = p0[1];
        int4 r10 = p1[0], r11 = p1[1];
        float v0 = x1v + h10; v0 = v0 > 0.f ? v0 : 0.2f * v0;
        float v1 = x1v + h11; v1 = v1 > 0.f ? v1 : 0.2f * v1;
        float w0 = __expf(v0);
        float w1 = has1 ? __expf(v1) : 0.f;
        div += w0 + w1;
        union { int4 v; ushort_t u[8]; } a, b;
        a.v = r00; b.v = r10;
        #pragma unroll
        for (int j = 0; j < 8; ++j) acc[j] += w0 * bf2f(a.u[j]) + w1 * bf2f(b.u[j]);
        a.v = r01; b.v = r11;
        #pragma unroll
        for (int j = 0; j < 8; ++j) acc[8 + j] += w0 * bf2f(a.u[j]) + w1 * bf2f(b.u[j]);
    }
    #pragma unroll
    for (int m = 8; m <= 32; m <<= 1) {
        #pragma unroll
        for (int j = 0; j < 16; ++j) acc[j] += __shfl_xor(acc[j], m, 64);
        div += __shfl_xor(div, m, 64);
    }
    if (g == 0) {
        float w2v = isA ? w2Ah[n] : w2Ph[n];
        const ushort_t* xb = (isA ? xAbf : xPbf) + (size_t)n * NHID + fl * 16;
        union { int4 v; ushort_t u[8]; } x0, x1u;
        x0.v = ((const int4*)xb)[0];
        x1u.v = ((const int4*)xb)[1];
        #pragma unroll
        for (int j = 0; j < 8; ++j) {
            acc[j] += w2v * bf2f(x0.u[j]);
            acc[8 + j] += w2v * bf2f(x1u.u[j]);
        }
        div += w2v;
        float inv = 1.f / div;
        const float* a2 = isA ? a2nA : a2nP;
        float s = 0.f;
        float o[16];
        #pragma unroll
        for (int j = 0; j < 16; ++j) {
            float v = acc[j] * inv;
            o[j] = v > 0.f ? v : (__expf(v) - 1.f);
            s += o[j] * a2[fl * 16 + j];
        }
        s += __shfl_xor(s, 1, 64);
        s += __shfl_xor(s, 2, 64);
        s += __shfl_xor(s, 4, 64);
        ushort_t* hb = (isA ? hAout : hPout) + (size_t)n * NHID + fl * 16;
        union { ushort_t u[8]; int4 v; } pk;
        #pragma unroll
        for (int j = 0; j < 8; ++j) pk.u[j] = (ushort_t)f2bf(o[j]);
        ((int4*)hb)[0] = pk.v;
        #pragma unroll
        for (int j = 0; j < 8; ++j) pk.u[j] = (ushort_t)f2bf(o[8 + j]);
        ((int4*)hb)[1] = pk.v;
        if (fl == 0) (isA ? h1Aout : h1Pout)[n] = s;
    }
}

extern "C" void kernel_launch(void* const* d_in, const int* in_sizes, int n_in,
                              void* d_out, int out_size, void* d_ws, size_t ws_size,
                              hipStream_t stream)
{
    const float* x_A  = (const float*)d_in[0];
    const float* x_P  = (const float*)d_in[1];
    const int*   sAP  = (const int*)d_in[2];
    const int*   tAP  = (const int*)d_in[3];
    const int*   sPA  = (const int*)d_in[4];
    const int*   tPA  = (const int*)d_in[5];
    const float* W1_A = (const float*)d_in[6];
    const float* b1_A = (const float*)d_in[7];
    const float* W1_P = (const float*)d_in[8];
    const float* b1_P = (const float*)d_in[9];
    const float* attn1 = (const float*)d_in[10];
    const float* attn2 = (const float*)d_in[11];
    const float* W2   = (const float*)d_in[12];
    const float* b2   = (const float*)d_in[13];
    float* out = (float*)d_out;
    int nE = in_sizes[2];

    char* ws = (char*)d_ws;
    size_t off = 0;
    auto alloc = [&](size_t bytes) -> void* {
        void* p = ws + off;
        off += (bytes + 255) & ~(size_t)255;
        return p;
    };
    ushort_t* xAbf  = (ushort_t*)alloc((size_t)NA * NHID * 2);
    ushort_t* xPbf  = (ushort_t*)alloc((size_t)NP * NHID * 2);
    ushort_t* hAbf[2] = {(ushort_t*)alloc((size_t)NA * NHID * 2),
                         (ushort_t*)alloc((size_t)NA * NHID * 2)};
    ushort_t* hPbf[2] = {(ushort_t*)alloc((size_t)NP * NHID * 2),
                         (ushort_t*)alloc((size_t)NP * NHID * 2)};
    float* x1A = (float*)alloc((size_t)3 * NA * 4);
    float* w2A = (float*)alloc((size_t)3 * NA * 4);
    float* x1P = (float*)alloc((size_t)3 * NP * 4);
    float* w2P = (float*)alloc((size_t)3 * NP * 4);
    float* h1Ai = (float*)alloc(NA * 4);
    float* h1Pi = (float*)alloc(NP * 4);
    float* h1Ab[2] = {(float*)alloc(NA * 4), (float*)alloc(NA * 4)};
    float* h1Pb[2] = {(float*)alloc(NP * 4), (float*)alloc(NP * 4)};
    int* cntA  = (int*)alloc(NA * 4);
    int* cntP  = (int*)alloc(NP * 4);
    int* slotsA = (int*)alloc((size_t)NA * CAP_A * 4);
    int* slotsP = (int*)alloc((size_t)NP * CAP_P * 4);
    short* WtA = (short*)alloc((size_t)NHID * NIN * 2);
    short* WtP = (short*)alloc((size_t)NHID * NIN * 2);
    short* Wt2 = (short*)alloc((size_t)NOUT * NHID * 2);

    // padded CSR (edge structure reused by all hops)
    hipMemsetAsync(cntA, 0, NA * 4, stream);
    hipMemsetAsync(cntP, 0, NP * 4, stream);
    fill_kernel<<<(2 * nE + 255) / 256, 256, 0, stream>>>(sAP, tAP, sPA, tPA,
                                                          cntA, slotsA, cntP, slotsP, nE);

    // weights -> bf16 transposed (one launch)
    prep_all<<<(2 * NHID * NIN + NOUT * NHID + 255) / 256, 256, 0, stream>>>(
        W1_A, W1_P, W2, WtA, WtP, Wt2);

    // merged projections -> bf16 h0
    int gA = (NA + 63) / 64, gP = (NP + 63) / 64;
    proj_mfma<<<gA + gP, 256, 0, stream>>>(x_A, x_P, WtA, WtP, b1_A, b1_P,
                                           xAbf, xPbf, gA);

    // x-side scalars for all hops (merged)
    xdots_kernel<<<(NA + NP + 3) / 4, 256, 0, stream>>>(
        xAbf, xPbf, attn1, attn2, x1A, w2A, h1Ai, x1P, w2P, h1Pi);

    const ushort_t* hAg = xAbf;
    const ushort_t* hPg = xPbf;
    const float* h1Ac = h1Ai;
    const float* h1Pc = h1Pi;

    for (int i = 0; i < HOPS; ++i) {
        int last = (i == HOPS - 1);
        int nodes = last ? NA : (NA + NP);
        const float* a2nA_ = last ? attn2 : attn2 + (size_t)((i + 1) * 2 + 1) * NHID;
        const float* a2nP_ = last ? attn2 : attn2 + (size_t)((i + 1) * 2 + 0) * NHID;
        agg_fused<<<(nodes + 3) / 4, 256, 0, stream>>>(
            xAbf, xPbf, hAg, hPg,
            x1A + (size_t)i * NA, x1P + (size_t)i * NP,
            w2A + (size_t)i * NA, w2P + (size_t)i * NP,
            h1Ac, h1Pc,
            cntA, slotsA, cntP, slotsP,
            a2nA_, a2nP_,
            hAbf[i & 1], hPbf[i & 1], h1Ab[i & 1], h1Pb[i & 1],
            nodes);
        hAg = hAbf[i & 1]; hPg = hPbf[i & 1];
        h1Ac = h1Ab[i & 1]; h1Pc = h1Pb[i & 1];
    }

    out_mfma<<<(NA + 63) / 64, 256, 0, stream>>>(hAg, Wt2, b2, out, NA);
}

// Round 6
// 478.644 us; speedup vs baseline: 1.0655x; 1.0003x over previous
//
#include <hip/hip_runtime.h>
#include <hip/hip_bf16.h>

#define HOPS 3
#define NA 50000
#define NP 100000
#define NIN 256
#define NHID 128
#define NOUT 64
#define CAP_A 64
#define CAP_P 40

typedef __attribute__((ext_vector_type(8))) short bf16x8;
typedef __attribute__((ext_vector_type(4))) float f32x4;
typedef unsigned short ushort_t;

__device__ inline short f2bf(float f) {
    __hip_bfloat16 h = __float2bfloat16(f);
    return *reinterpret_cast<short*>(&h);
}
__device__ inline float bf2f(unsigned short u) {
    unsigned v = ((unsigned)u) << 16;
    return __uint_as_float(v);
}

// async global -> LDS, 16 bytes per lane (linear dest: base + lane*16)
__device__ inline void gload16(const void* g, void* l) {
    __builtin_amdgcn_global_load_lds(
        (const __attribute__((address_space(1))) unsigned int*)g,
        (__attribute__((address_space(3))) unsigned int*)l, 16, 0, 0);
}

// ---------- all weight transposes+converts in one launch ----------
__global__ void prep_all(const float* __restrict__ W1_A, const float* __restrict__ W1_P,
                         const float* __restrict__ W2,
                         short* __restrict__ WtA, short* __restrict__ WtP,
                         short* __restrict__ Wt2)
{
    int idx = blockIdx.x * 256 + threadIdx.x;
    const int S1 = NHID * NIN;
    if (idx < S1) {
        int n = idx / NIN, k = idx - n * NIN;
        WtA[idx] = f2bf(W1_A[(size_t)k * NHID + n]);
    } else if (idx < 2 * S1) {
        int j = idx - S1;
        int n = j / NIN, k = j - n * NIN;
        WtP[j] = f2bf(W1_P[(size_t)k * NHID + n]);
    } else if (idx < 2 * S1 + NOUT * NHID) {
        int j = idx - 2 * S1;
        int n = j / NHID, k = j - n * NHID;
        Wt2[j] = f2bf(W2[(size_t)k * NOUT + n]);
    }
}

// ---------- merged projection: Cbf = bf16(relu(X @ W1 + b1)) for A and P ----------
// 256 thr / 4 waves, tile 64 rows x 128 cols, BK=64, double-buffered bf16 LDS,
// ONE barrier per K-step. Global loads issued one full compute phase ahead via
// 2 register slots; f32->bf16 conversion done at staging time.
// mfma_f32_16x16x32_bf16: A row=l&15,k=(l>>4)*8+j ; B col=l&15 ; D col=l&15,row=(l>>4)*4+j
__global__ __launch_bounds__(256) void proj_mfma(
        const float* __restrict__ xA, const float* __restrict__ xP,
        const short* __restrict__ WtA_, const short* __restrict__ WtP_,
        const float* __restrict__ bA, const float* __restrict__ bP,
        ushort_t* __restrict__ CA, ushort_t* __restrict__ CP, int gA)
{
    __shared__ ushort_t Ab[2][64][72];   // 18.4 KB, row stride 144B
    const int tid = threadIdx.x;
    const int wv = tid >> 6, l = tid & 63;
    const int fl = l & 15, kg = l >> 4;   // MFMA roles
    const int sr = tid >> 2;              // staging row 0..63
    const int sq = tid & 3;               // staging quarter (16 f32 each)

    const int bid = blockIdx.x;
    const bool isA = bid < gA;
    const float* X = isA ? xA : xP;
    const short* Wt = isA ? WtA_ : WtP_;
    const float* bias = isA ? bA : bP;
    ushort_t* C = isA ? CA : CP;
    const int M = isA ? NA : NP;
    const int Rbase = (isA ? bid : bid - gA) * 64;

    int gr = Rbase + sr; if (gr >= M) gr = M - 1;
    const float* srow = X + (size_t)gr * NIN + sq * 16;

    f32x4 acc[8];
    #pragma unroll
    for (int c = 0; c < 8; ++c) acc[c] = (f32x4){0.f, 0.f, 0.f, 0.f};

    float4 st[2][4];
    auto LOADREG = [&](int s, int t) {
        #pragma unroll
        for (int i = 0; i < 4; ++i)
            st[s][i] = *(const float4*)(srow + t * 64 + i * 4);
    };
    auto CVTWRITE = [&](int b, int s) {
        union { ushort_t u[8]; int4 v; } p0, p1;
        p0.u[0] = (ushort_t)f2bf(st[s][0].x); p0.u[1] = (ushort_t)f2bf(st[s][0].y);
        p0.u[2] = (ushort_t)f2bf(st[s][0].z); p0.u[3] = (ushort_t)f2bf(st[s][0].w);
        p0.u[4] = (ushort_t)f2bf(st[s][1].x); p0.u[5] = (ushort_t)f2bf(st[s][1].y);
        p0.u[6] = (ushort_t)f2bf(st[s][1].z); p0.u[7] = (ushort_t)f2bf(st[s][1].w);
        p1.u[0] = (ushort_t)f2bf(st[s][2].x); p1.u[1] = (ushort_t)f2bf(st[s][2].y);
        p1.u[2] = (ushort_t)f2bf(st[s][2].z); p1.u[3] = (ushort_t)f2bf(st[s][2].w);
        p1.u[4] = (ushort_t)f2bf(st[s][3].x); p1.u[5] = (ushort_t)f2bf(st[s][3].y);
        p1.u[6] = (ushort_t)f2bf(st[s][3].z); p1.u[7] = (ushort_t)f2bf(st[s][3].w);
        *(int4*)&Ab[b][sr][sq * 16]     = p0.v;
        *(int4*)&Ab[b][sr][sq * 16 + 8] = p1.v;
    };
    auto COMPUTE = [&](int b, int k0) {
        bf16x8 Bf[16];
        #pragma unroll
        for (int ks = 0; ks < 2; ++ks)
            #pragma unroll
            for (int c = 0; c < 8; ++c)
                Bf[ks * 8 + c] = *(const bf16x8*)(Wt + (size_t)(c * 16 + fl) * NIN
                                                  + k0 + ks * 32 + kg * 8);
        #pragma unroll
        for (int ks = 0; ks < 2; ++ks) {
            bf16x8 af = *(const bf16x8*)&Ab[b][wv * 16 + fl][ks * 32 + kg * 8];
            #pragma unroll
            for (int c = 0; c < 8; ++c)
                acc[c] = __builtin_amdgcn_mfma_f32_16x16x32_bf16(af, Bf[ks * 8 + c],
                                                                 acc[c], 0, 0, 0);
        }
    };

    LOADREG(0, 0);
    LOADREG(1, 1);
    CVTWRITE(0, 0);
    __syncthreads();
    // t = 0
    LOADREG(0, 2);           // issue chunk2 early
    COMPUTE(0, 0);
    CVTWRITE(1, 1);
    __syncthreads();
    // t = 1
    LOADREG(1, 3);           // issue chunk3 early
    COMPUTE(1, 64);
    CVTWRITE(0, 0);          // chunk2
    __syncthreads();
    // t = 2
    COMPUTE(0, 128);
    CVTWRITE(1, 1);          // chunk3
    __syncthreads();
    // t = 3
    COMPUTE(1, 192);

    #pragma unroll
    for (int c = 0; c < 8; ++c) {
        int col = c * 16 + fl;
        float bb = bias[col];
        #pragma unroll
        for (int j = 0; j < 4; ++j) {
            int grow = Rbase + wv * 16 + kg * 4 + j;
            if (grow < M) {
                float v = fmaxf(acc[c][j] + bb, 0.f);
                C[(size_t)grow * NHID + col] = (ushort_t)f2bf(v);
            }
        }
    }
}

// ---------- output: C[M,64] = Abf[M,128] @ W2 + b2, single-stage MFMA ----------
__global__ __launch_bounds__(256) void out_mfma(const ushort_t* __restrict__ Abf,
        const short* __restrict__ Wt, const float* __restrict__ b,
        float* __restrict__ C, int M)
{
    __shared__ ushort_t Sb[64 * 128];   // 16KB
    const int tid = threadIdx.x;
    const int wv = tid >> 6, l = tid & 63;
    const int fl = l & 15, kg = l >> 4;
    const int br = blockIdx.x * 64;
    const int srow = l >> 4, schk = l & 15;

    #pragma unroll
    for (int i = 0; i < 4; ++i) {
        int r = (wv * 4 + i) * 4 + srow;
        int gr = br + r; if (gr >= M) gr = M - 1;
        int ck = (schk ^ (r & 7)) * 8;
        gload16(Abf + (size_t)gr * NHID + ck, &Sb[(wv * 4 + i) * 512]);
    }

    f32x4 acc[4];
    #pragma unroll
    for (int c = 0; c < 4; ++c) acc[c] = (f32x4){0.f, 0.f, 0.f, 0.f};

    bf16x8 Bf[16];
    #pragma unroll
    for (int ks = 0; ks < 4; ++ks)
        #pragma unroll
        for (int cc = 0; cc < 4; ++cc)
            Bf[ks * 4 + cc] = *(const bf16x8*)(Wt + (size_t)(cc * 16 + fl) * NHID
                                               + ks * 32 + kg * 8);
    __syncthreads();

    const int R = wv * 16 + fl;
    const int rx = R & 7;
    #pragma unroll
    for (int ks = 0; ks < 4; ++ks) {
        int chunk = (ks * 4 + kg) ^ rx;
        bf16x8 af = *(const bf16x8*)&Sb[R * 128 + chunk * 8];
        #pragma unroll
        for (int cc = 0; cc < 4; ++cc)
            acc[cc] = __builtin_amdgcn_mfma_f32_16x16x32_bf16(af, Bf[ks * 4 + cc],
                                                              acc[cc], 0, 0, 0);
    }

    #pragma unroll
    for (int cc = 0; cc < 4; ++cc) {
        int col = cc * 16 + fl;
        float bb = b[col];
        #pragma unroll
        for (int j = 0; j < 4; ++j) {
            int grow = br + wv * 16 + kg * 4 + j;
            if (grow < M) C[(size_t)grow * NOUT + col] = acc[cc][j] + bb;
        }
    }
}

// ---------- merged padded-CSR fill ----------
__global__ void fill_kernel(const int* __restrict__ sA, const int* __restrict__ tA,
                            const int* __restrict__ sP, const int* __restrict__ tP,
                            int* __restrict__ cntA, int* __restrict__ slotsA,
                            int* __restrict__ cntP, int* __restrict__ slotsP, int nE)
{
    int e = blockIdx.x * 256 + threadIdx.x;
    if (e < nE) {
        int si = sA[e];
        int c = atomicAdd(&cntA[si], 1);
        if (c < CAP_A) slotsA[(size_t)si * CAP_A + c] = tA[e];
    } else if (e < 2 * nE) {
        int k = e - nE;
        int si = sP[k];
        int c = atomicAdd(&cntP[si], 1);
        if (c < CAP_P) slotsP[(size_t)si * CAP_P + c] = tP[k];
    }
}

// ---------- merged x-side scalars for ALL hops ----------
__global__ void xdots_kernel(const ushort_t* __restrict__ xAbf, const ushort_t* __restrict__ xPbf,
                             const float* __restrict__ attn1, const float* __restrict__ attn2,
                             float* __restrict__ x1A, float* __restrict__ w2A, float* __restrict__ h1Ai,
                             float* __restrict__ x1P, float* __restrict__ w2P, float* __restrict__ h1Pi)
{
    int wid = (blockIdx.x * blockDim.x + threadIdx.x) >> 6;
    int lane = threadIdx.x & 63;
    if (wid >= NA + NP) return;
    bool isA = wid < NA;
    int n = isA ? wid : wid - NA;
    int etype = isA ? 0 : 1;
    const ushort_t* x = (isA ? xAbf : xPbf) + (size_t)n * NHID;
    ushort2 xv = *(const ushort2*)(x + lane * 2);
    float xa = bf2f(xv.x), xb = bf2f(xv.y);
    float s[7];
    #pragma unroll
    for (int i = 0; i < 3; ++i) {
        float2 a1v = *(const float2*)(attn1 + (size_t)(i * 2 + etype) * NHID + lane * 2);
        float2 a2v = *(const float2*)(attn2 + (size_t)(i * 2 + etype) * NHID + lane * 2);
        s[i]     = xa * a1v.x + xb * a1v.y;
        s[3 + i] = xa * a2v.x + xb * a2v.y;
    }
    float2 a2o = *(const float2*)(attn2 + (size_t)(1 - etype) * NHID + lane * 2);
    s[6] = xa * a2o.x + xb * a2o.y;
    #pragma unroll
    for (int m = 32; m; m >>= 1)
        #pragma unroll
        for (int i = 0; i < 7; ++i) s[i] += __shfl_xor(s[i], m, 64);
    if (lane == 0) {
        int N = isA ? NA : NP;
        float* x1 = isA ? x1A : x1P;
        float* w2 = isA ? w2A : w2P;
        #pragma unroll
        for (int i = 0; i < 3; ++i) {
            x1[(size_t)i * N + n] = s[i];
            float v = s[i] + s[3 + i];
            v = v > 0.f ? v : 0.2f * v;
            w2[(size_t)i * N + n] = __expf(v);
        }
        (isA ? h1Ai : h1Pi)[n] = s[6];
    }
}

// ---------- fused A+P aggregation, scores computed in-kernel ----------
// wave/node, 8 edge-groups x 8 feature-lanes (16 floats each), 1 edge/group/round
__global__ __launch_bounds__(256) void agg_fused(
    const ushort_t* __restrict__ xAbf, const ushort_t* __restrict__ xPbf,
    const ushort_t* __restrict__ hAg, const ushort_t* __restrict__ hPg,
    const float* __restrict__ x1Ah, const float* __restrict__ x1Ph,
    const float* __restrict__ w2Ah, const float* __restrict__ w2Ph,
    const float* __restrict__ h1Agc, const float* __restrict__ h1Pgc,
    const int* __restrict__ cntA, const int* __restrict__ slotsA,
    const int* __restrict__ cntP, const int* __restrict__ slotsP,
    const float* __restrict__ a2nA, const float* __restrict__ a2nP,
    ushort_t* __restrict__ hAout, ushort_t* __restrict__ hPout,
    float* __restrict__ h1Aout, float* __restrict__ h1Pout,
    int nodes)
{
    int wid = (blockIdx.x * blockDim.x + threadIdx.x) >> 6;
    int lane = threadIdx.x & 63;
    if (wid >= nodes) return;
    int g = lane >> 3, fl = lane & 7;
    bool isA = wid < NA;
    int n = isA ? wid : wid - NA;
    int deg; const int* sl; const ushort_t* hbf; const float* h1g; float x1v;
    if (isA) {
        deg = cntA[n]; if (deg > CAP_A) deg = CAP_A;
        sl = slotsA + (size_t)n * CAP_A; hbf = hPg; h1g = h1Pgc; x1v = x1Ah[n];
    } else {
        deg = cntP[n]; if (deg > CAP_P) deg = CAP_P;
        sl = slotsP + (size_t)n * CAP_P; hbf = hAg; h1g = h1Agc; x1v = x1Ph[n];
    }

    float acc[16] = {};
    float div = 0.f;
    for (int e = g; e < deg; e += 8) {
        int t0 = sl[e];
        float h10 = h1g[t0];
        const int4* p0 = (const int4*)(hbf + (size_t)t0 * NHID + fl * 16);
        int4 r00 = p0[0], r01 = p0[1];
        float v0 = x1v + h10; v0 = v0 > 0.f ? v0 : 0.2f * v0;
        float w0 = __expf(v0);
        div += w0;
        union { int4 v; ushort_t u[8]; } a;
        a.v = r00;
        #pragma unroll
        for (int j = 0; j < 8; ++j) acc[j] += w0 * bf2f(a.u[j]);
        a.v = r01;
        #pragma unroll
        for (int j = 0; j < 8; ++j) acc[8 + j] += w0 * bf2f(a.u[j]);
    }
    #pragma unroll
    for (int m = 8; m <= 32; m <<= 1) {
        #pragma unroll
        for (int j = 0; j < 16; ++j) acc[j] += __shfl_xor(acc[j], m, 64);
        div += __shfl_xor(div, m, 64);
    }
    if (g == 0) {
        float w2v = isA ? w2Ah[n] : w2Ph[n];
        const ushort_t* xb = (isA ? xAbf : xPbf) + (size_t)n * NHID + fl * 16;
        union { int4 v; ushort_t u[8]; } x0, x1u;
        x0.v = ((const int4*)xb)[0];
        x1u.v = ((const int4*)xb)[1];
        #pragma unroll
        for (int j = 0; j < 8; ++j) {
            acc[j] += w2v * bf2f(x0.u[j]);
            acc[8 + j] += w2v * bf2f(x1u.u[j]);
        }
        div += w2v;
        float inv = 1.f / div;
        const float* a2 = isA ? a2nA : a2nP;
        float s = 0.f;
        float o[16];
        #pragma unroll
        for (int j = 0; j < 16; ++j) {
            float v = acc[j] * inv;
            o[j] = v > 0.f ? v : (__expf(v) - 1.f);
            s += o[j] * a2[fl * 16 + j];
        }
        s += __shfl_xor(s, 1, 64);
        s += __shfl_xor(s, 2, 64);
        s += __shfl_xor(s, 4, 64);
        ushort_t* hb = (isA ? hAout : hPout) + (size_t)n * NHID + fl * 16;
        union { ushort_t u[8]; int4 v; } pk;
        #pragma unroll
        for (int j = 0; j < 8; ++j) pk.u[j] = (ushort_t)f2bf(o[j]);
        ((int4*)hb)[0] = pk.v;
        #pragma unroll
        for (int j = 0; j < 8; ++j) pk.u[j] = (ushort_t)f2bf(o[8 + j]);
        ((int4*)hb)[1] = pk.v;
        if (fl == 0) (isA ? h1Aout : h1Pout)[n] = s;
    }
}

extern "C" void kernel_launch(void* const* d_in, const int* in_sizes, int n_in,
                              void* d_out, int out_size, void* d_ws, size_t ws_size,
                              hipStream_t stream)
{
    const float* x_A  = (const float*)d_in[0];
    const float* x_P  = (const float*)d_in[1];
    const int*   sAP  = (const int*)d_in[2];
    const int*   tAP  = (const int*)d_in[3];
    const int*   sPA  = (const int*)d_in[4];
    const int*   tPA  = (const int*)d_in[5];
    const float* W1_A = (const float*)d_in[6];
    const float* b1_A = (const float*)d_in[7];
    const float* W1_P = (const float*)d_in[8];
    const float* b1_P = (const float*)d_in[9];
    const float* attn1 = (const float*)d_in[10];
    const float* attn2 = (const float*)d_in[11];
    const float* W2   = (const float*)d_in[12];
    const float* b2   = (const float*)d_in[13];
    float* out = (float*)d_out;
    int nE = in_sizes[2];

    char* ws = (char*)d_ws;
    size_t off = 0;
    auto alloc = [&](size_t bytes) -> void* {
        void* p = ws + off;
        off += (bytes + 255) & ~(size_t)255;
        return p;
    };
    ushort_t* xAbf  = (ushort_t*)alloc((size_t)NA * NHID * 2);
    ushort_t* xPbf  = (ushort_t*)alloc((size_t)NP * NHID * 2);
    ushort_t* hAbf[2] = {(ushort_t*)alloc((size_t)NA * NHID * 2),
                         (ushort_t*)alloc((size_t)NA * NHID * 2)};
    ushort_t* hPbf[2] = {(ushort_t*)alloc((size_t)NP * NHID * 2),
                         (ushort_t*)alloc((size_t)NP * NHID * 2)};
    float* x1A = (float*)alloc((size_t)3 * NA * 4);
    float* w2A = (float*)alloc((size_t)3 * NA * 4);
    float* x1P = (float*)alloc((size_t)3 * NP * 4);
    float* w2P = (float*)alloc((size_t)3 * NP * 4);
    float* h1Ai = (float*)alloc(NA * 4);
    float* h1Pi = (float*)alloc(NP * 4);
    float* h1Ab[2] = {(float*)alloc(NA * 4), (float*)alloc(NA * 4)};
    float* h1Pb[2] = {(float*)alloc(NP * 4), (float*)alloc(NP * 4)};
    int* cntA  = (int*)alloc(NA * 4);
    int* cntP  = (int*)alloc(NP * 4);
    int* slotsA = (int*)alloc((size_t)NA * CAP_A * 4);
    int* slotsP = (int*)alloc((size_t)NP * CAP_P * 4);
    short* WtA = (short*)alloc((size_t)NHID * NIN * 2);
    short* WtP = (short*)alloc((size_t)NHID * NIN * 2);
    short* Wt2 = (short*)alloc((size_t)NOUT * NHID * 2);

    // padded CSR (edge structure reused by all hops)
    hipMemsetAsync(cntA, 0, NA * 4, stream);
    hipMemsetAsync(cntP, 0, NP * 4, stream);
    fill_kernel<<<(2 * nE + 255) / 256, 256, 0, stream>>>(sAP, tAP, sPA, tPA,
                                                          cntA, slotsA, cntP, slotsP, nE);

    // weights -> bf16 transposed (one launch)
    prep_all<<<(2 * NHID * NIN + NOUT * NHID + 255) / 256, 256, 0, stream>>>(
        W1_A, W1_P, W2, WtA, WtP, Wt2);

    // merged projections -> bf16 h0
    int gA = (NA + 63) / 64, gP = (NP + 63) / 64;
    proj_mfma<<<gA + gP, 256, 0, stream>>>(x_A, x_P, WtA, WtP, b1_A, b1_P,
                                           xAbf, xPbf, gA);

    // x-side scalars for all hops (merged)
    xdots_kernel<<<(NA + NP + 3) / 4, 256, 0, stream>>>(
        xAbf, xPbf, attn1, attn2, x1A, w2A, h1Ai, x1P, w2P, h1Pi);

    const ushort_t* hAg = xAbf;
    const ushort_t* hPg = xPbf;
    const float* h1Ac = h1Ai;
    const float* h1Pc = h1Pi;

    for (int i = 0; i < HOPS; ++i) {
        int last = (i == HOPS - 1);
        int nodes = last ? NA : (NA + NP);
        const float* a2nA_ = last ? attn2 : attn2 + (size_t)((i + 1) * 2 + 1) * NHID;
        const float* a2nP_ = last ? attn2 : attn2 + (size_t)((i + 1) * 2 + 0) * NHID;
        agg_fused<<<(nodes + 3) / 4, 256, 0, stream>>>(
            xAbf, xPbf, hAg, hPg,
            x1A + (size_t)i * NA, x1P + (size_t)i * NP,
            w2A + (size_t)i * NA, w2P + (size_t)i * NP,
            h1Ac, h1Pc,
            cntA, slotsA, cntP, slotsP,
            a2nA_, a2nP_,
            hAbf[i & 1], hPbf[i & 1], h1Ab[i & 1], h1Pb[i & 1],
            nodes);
        hAg = hAbf[i & 1]; hPg = hPbf[i & 1];
        h1Ac = h1Ab[i & 1]; h1Pc = h1Pb[i & 1];
    }

    out_mfma<<<(NA + 63) / 64, 256, 0, stream>>>(hAg, Wt2, b2, out, NA);
}